// Round 8
// baseline (590.255 us; speedup 1.0000x reference)
//
#include <hip/hip_runtime.h>
#include <hip/hip_bf16.h>
#include <stdint.h>

// ---------------------------------------------------------------------------
// GroupedQueryAttention: hidden(B,S,4096) -> fused QKV proj -> RoPE -> causal
// GQA flash attention -> out proj.  B=2 S=2048 H=32 Hk=8 D=128.  bf16 MFMA.
// ---------------------------------------------------------------------------

#define HIDDEN 4096
#define NH 32
#define NKV 8
#define HD 128
#define SLEN 2048
#define BATCH 2
#define QKVLD 6144  // fused QKV row stride (cols: Q 0..4095, K 4096..5119, V 5120..6143)

typedef __attribute__((ext_vector_type(8))) short bf16x8;
typedef __attribute__((ext_vector_type(4))) float f32x4;

__device__ __forceinline__ unsigned short f2bf(float f) {
  __hip_bfloat16 h = __float2bfloat16(f);
  return *reinterpret_cast<unsigned short*>(&h);
}
__device__ __forceinline__ float bf2f(unsigned short h) {
  union { uint32_t u; float f; } v; v.u = ((uint32_t)h) << 16;
  return v.f;
}
__device__ __forceinline__ void gload_lds16(const void* g, void* l) {
  __builtin_amdgcn_global_load_lds(
      (const __attribute__((address_space(1))) unsigned int*)g,
      (__attribute__((address_space(3))) unsigned int*)l, 16, 0, 0);
}

// ---------------------------------------------------------------------------
// fp32 -> bf16 convert, 8 elems/thread. n = grid*2048 exactly.
// ---------------------------------------------------------------------------
__global__ __launch_bounds__(256) void cvt_f32_bf16(const float* __restrict__ in,
                                                    unsigned short* __restrict__ out) {
  size_t i = ((size_t)blockIdx.x * 256 + threadIdx.x) * 8;
  f32x4 a = *(const f32x4*)&in[i];
  f32x4 b = *(const f32x4*)&in[i + 4];
  bf16x8 o;
#pragma unroll
  for (int j = 0; j < 4; ++j) { o[j] = (short)f2bf(a[j]); o[4 + j] = (short)f2bf(b[j]); }
  *(bf16x8*)&out[i] = o;
}

// ---------------------------------------------------------------------------
// GEMM  C(M,N) = A(M,K) @ B(N,K)^T, bf16 in, OutT out.
// m201-style 8-phase schedule: 256x256 tile, BK=64, 8 waves (2Mx4N = 128x64
// per wave), 512 threads.  LDS = 2 buffers x 64KB; each buffer = 4 K-split
// half-tiles {A-k0, A-k1, B-k0, B-k1} of [256 rows][4 chunks] (chunk=16B).
// Per K-tile, 4 phases, each:
//   {4-or-8 ds_read_b128 | stage 1 half-tile (2 gload_lds16) | s_barrier |
//    lgkmcnt(0)+sched_barrier | setprio(1) 16 MFMA setprio(0) | s_barrier}
// Stage targets only regions whose reads completed >=1 phase ago (operands
// are in registers by then) -> race-free by barrier construction:
//   ph1: A-k1(t+1)->other buf | reads A-k0 mi0-3 + B-k0 | MFMA mi0-3 k0
//   ph2: B-k0(t+2)            | reads A-k0 mi4-7        | MFMA mi4-7 k0
//   ph3: A-k0(t+2)            | reads A-k1 mi0-3 + B-k1 | MFMA mi0-3 k1
//   ph4: B-k1(t+2)            | reads A-k1 mi4-7        | MFMA mi4-7 k1
// Boundary: counted s_waitcnt vmcnt(6) (T4: 3 half-tiles stay in flight),
// never drained in steady state.  Swizzle (verified r5, 0 conflicts): LDS
// dest linear, global source chunk cc ^ ((row>>1)&3), read XORs same term.
// M,N multiples of 256; K multiple of 64 (>=192); grid % 8 == 0.
// ---------------------------------------------------------------------------
__device__ __forceinline__ void store_out(unsigned short* C, size_t i, float v) { C[i] = f2bf(v); }
__device__ __forceinline__ void store_out(float* C, size_t i, float v) { C[i] = v; }

template <typename OutT>
__global__ __launch_bounds__(512, 2)
void gemm_bt256(const unsigned short* __restrict__ A, const unsigned short* __restrict__ B,
                OutT* __restrict__ C, int M, int N, int K) {
  // 2 buffers x 4096 chunks (A-k0 | A-k1 | B-k0 | B-k1, 1024 chunks each)
  __shared__ __align__(16) unsigned short lds[2 * 4096 * 8];

  const int tid = threadIdx.x;
  const int lane = tid & 63, w = tid >> 6;
  const int lr = lane & 15, lg = lane >> 4;
  const int wr = w >> 2, wc = w & 3;  // 2 x 4 wave grid
  const int rsw = (lr >> 1) & 3;      // read-side swizzle term

  const int nbn = N >> 8;
  const int nwg = gridDim.x;
  int wg = (int)blockIdx.x;
  wg = (wg & 7) * (nwg >> 3) + (wg >> 3);  // XCD-aware swizzle (nwg%8==0)
  const int bm = wg / nbn, bn = wg % nbn;

  const unsigned short* Ab = A + (size_t)bm * 256 * K;
  const unsigned short* Bb = B + (size_t)bn * 256 * K;

  f32x4 acc[8][4] = {};

  // stage one half-tile (16KB = 1024 chunks, 2 gload_lds16/thread).
  // isA in {1,0}; ks in {0,1}; tile -> buf[tile&1].
  auto stage_half = [&](int isA, int ks, int tile) {
    const unsigned short* gb = isA ? Ab : Bb;
    const int rb = (tile & 1) * 4096 + (isA ? 0 : 2048) + ks * 1024;
    const int kcol = tile * 64 + ks * 32;
#pragma unroll
    for (int j = 0; j < 2; ++j) {
      int L = tid + j * 512;
      int row = L >> 2, cc = L & 3;
      int scc = cc ^ ((row >> 1) & 3);
      gload_lds16(gb + (size_t)row * K + kcol + scc * 8, lds + (size_t)(rb + L) * 8);
    }
  };
  auto read_a4 = [&](bf16x8* dst, int ks, int mi0, int p) {
#pragma unroll
    for (int i = 0; i < 4; ++i) {
      int row = wr * 128 + (mi0 + i) * 16 + lr;
      dst[i] = *(const bf16x8*)&lds[(size_t)(p * 4096 + ks * 1024 + row * 4 + (lg ^ rsw)) * 8];
    }
  };
  auto read_b4 = [&](bf16x8* dst, int ks, int p) {
#pragma unroll
    for (int i = 0; i < 4; ++i) {
      int row = wc * 64 + i * 16 + lr;
      dst[i] =
          *(const bf16x8*)&lds[(size_t)(p * 4096 + 2048 + ks * 1024 + row * 4 + (lg ^ rsw)) * 8];
    }
  };

#define PHASE_SYNC()                                    \
  __builtin_amdgcn_s_barrier();                         \
  asm volatile("s_waitcnt lgkmcnt(0)" ::: "memory");    \
  __builtin_amdgcn_sched_barrier(0)

#define MFMA16(afq, bq, mb)                                                                   \
  __builtin_amdgcn_s_setprio(1);                                                              \
  _Pragma("unroll") for (int i_ = 0; i_ < 4; ++i_) _Pragma("unroll") for (int n_ = 0; n_ < 4; \
                                                                          ++n_) acc[mb + i_]  \
      [n_] = __builtin_amdgcn_mfma_f32_16x16x32_bf16(afq[i_], bq[n_], acc[mb + i_][n_], 0, 0, 0); \
  __builtin_amdgcn_s_setprio(0);                                                              \
  __builtin_amdgcn_s_barrier()

  const int NT = K >> 6;

  // prologue: tile 0 fully + 3 halves of tile 1; wait tile 0 (6 in flight)
  stage_half(1, 0, 0); stage_half(0, 0, 0); stage_half(1, 1, 0); stage_half(0, 1, 0);
  if (NT > 1) { stage_half(0, 0, 1); stage_half(1, 0, 1); stage_half(0, 1, 1); }
  if (NT > 1) asm volatile("s_waitcnt vmcnt(6)" ::: "memory");
  else        asm volatile("s_waitcnt vmcnt(0)" ::: "memory");
  __builtin_amdgcn_s_barrier();
  asm volatile("" ::: "memory");

#pragma unroll 1
  for (int t = 0; t < NT; ++t) {
    const int p = t & 1;
    bf16x8 afq[4], afq2[4], bq0[4], bq1[4];

    // ---- phase 1: reads A-k0 mi0-3 + B-k0 | stage A-k1(t+1) | MFMA k0 lo ----
    read_a4(afq, 0, 0, p);
    read_b4(bq0, 0, p);
    if (t + 1 < NT) stage_half(1, 1, t + 1);
    PHASE_SYNC();
    MFMA16(afq, bq0, 0);

    // ---- phase 2: reads A-k0 mi4-7 | stage B-k0(t+2) | MFMA k0 hi ----
    read_a4(afq2, 0, 4, p);
    if (t + 2 < NT) stage_half(0, 0, t + 2);
    PHASE_SYNC();
    MFMA16(afq2, bq0, 4);

    // ---- phase 3: reads A-k1 mi0-3 + B-k1 | stage A-k0(t+2) | MFMA k1 lo ----
    read_a4(afq, 1, 0, p);
    read_b4(bq1, 1, p);
    if (t + 2 < NT) stage_half(1, 0, t + 2);
    PHASE_SYNC();
    MFMA16(afq, bq1, 0);

    // ---- phase 4: reads A-k1 mi4-7 | stage B-k1(t+2) | MFMA k1 hi ----
    read_a4(afq2, 1, 4, p);
    if (t + 2 < NT) stage_half(0, 1, t + 2);
    PHASE_SYNC();
    MFMA16(afq2, bq1, 4);

    // ---- tile boundary: counted vmcnt (3 half-tiles in flight) ----
    if (t + 2 < NT)      asm volatile("s_waitcnt vmcnt(6)" ::: "memory");
    else if (t + 1 < NT) asm volatile("s_waitcnt vmcnt(0)" ::: "memory");
    __builtin_amdgcn_s_barrier();
    asm volatile("" ::: "memory");
  }

#pragma unroll
  for (int mi = 0; mi < 8; ++mi)
#pragma unroll
    for (int ni = 0; ni < 4; ++ni)
#pragma unroll
      for (int r = 0; r < 4; ++r) {
        size_t row = (size_t)bm * 256 + wr * 128 + mi * 16 + lg * 4 + r;
        size_t col = (size_t)bn * 256 + wc * 64 + ni * 16 + lr;
        store_out(C, row * N + col, acc[mi][ni][r]);
      }
#undef PHASE_SYNC
#undef MFMA16
}

// ---------------------------------------------------------------------------
// RoPE tables + apply
// ---------------------------------------------------------------------------
__global__ __launch_bounds__(256) void rope_tables(float* __restrict__ ct, float* __restrict__ st) {
  int idx = blockIdx.x * 256 + threadIdx.x;  // S*64
  int s = idx >> 6, j = idx & 63;
  float inv = exp2f(-(float)j * (13.287712379549449f / 64.f));
  float f = (float)s * inv;
  ct[idx] = cosf(f);
  st[idx] = sinf(f);
}

__global__ __launch_bounds__(256) void rope_apply(unsigned short* __restrict__ X, int ld,
                                                  const float* __restrict__ ct,
                                                  const float* __restrict__ st, int heads) {
  int idx = blockIdx.x * 256 + threadIdx.x;
  int jc = (idx & 7) * 8;
  int t2 = idx >> 3;
  int hh = t2 % heads;
  int row = t2 / heads;
  int s = row & (SLEN - 1);
  unsigned short* p = X + (size_t)row * ld + hh * HD;
  bf16x8 lo = *(bf16x8*)&p[jc];
  bf16x8 hi = *(bf16x8*)&p[64 + jc];
  bf16x8 nlo, nhi;
#pragma unroll
  for (int j = 0; j < 8; ++j) {
    float c = ct[s * 64 + jc + j];
    float sn = st[s * 64 + jc + j];
    float xl = bf2f((unsigned short)(lo[j]));
    float xh = bf2f((unsigned short)(hi[j]));
    nlo[j] = (short)f2bf(xl * c - xh * sn);
    nhi[j] = (short)f2bf(xh * c + xl * sn);
  }
  *(bf16x8*)&p[jc] = nlo;
  *(bf16x8*)&p[64 + jc] = nhi;
}

// ---------------------------------------------------------------------------
// V (rows B*S at stride ld, 1024 cols) -> VT (B, NKV, HD, S)
// ---------------------------------------------------------------------------
__global__ __launch_bounds__(256) void transpose_v(const unsigned short* __restrict__ Vsrc, int ld,
                                                   unsigned short* __restrict__ VT) {
  __shared__ unsigned short tile[64][66];
  const int t = threadIdx.x;
  const int bs = blockIdx.x;
  const int bd = blockIdx.y;
  const int b = bs >> 5;
  const int s0 = (bs & 31) * 64;
  const int d0 = bd * 64;
#pragma unroll
  for (int it = 0; it < 2; ++it) {
    int si = (t >> 3) + it * 32;
    int dj = (t & 7) * 8;
    bf16x8 v = *(const bf16x8*)&Vsrc[(size_t)(b * SLEN + s0 + si) * ld + d0 + dj];
#pragma unroll
    for (int j = 0; j < 8; ++j) tile[si][dj + j] = (unsigned short)(v[j]);
  }
  __syncthreads();
#pragma unroll
  for (int it = 0; it < 2; ++it) {
    int di = (t >> 3) + it * 32;
    int sj = (t & 7) * 8;
    bf16x8 o;
#pragma unroll
    for (int j = 0; j < 8; ++j) o[j] = (short)tile[sj + j][di];
    int c = d0 + di;
    int kvh = c >> 7, d = c & 127;
    *(bf16x8*)&VT[(((size_t)b * NKV + kvh) * HD + d) * SLEN + s0 + sj] = o;
  }
}

// ---------------------------------------------------------------------------
// Flash attention (round-3 version, validated).
// ---------------------------------------------------------------------------
__global__ __launch_bounds__(256, 2)
void attn_fwd(const unsigned short* __restrict__ QKV, const unsigned short* __restrict__ VTm,
              unsigned short* __restrict__ Om) {
  const int blk = blockIdx.x;            // 0..511
  const int xcd = blk & 7, jj = blk >> 3;
  const int g = xcd + ((jj >> 5) << 3);  // (b,kvh) group 0..15, pinned per XCD
  const int pair = jj & 31;
  const int kvh = g & 7, b = g >> 3;
  const int tid = threadIdx.x;
  const int lane = tid & 63, w = tid >> 6;
  const int lr = lane & 15, lg = lane >> 4;
  const int h = kvh * 4 + w;

  __shared__ __align__(16) unsigned short Ksm[64 * 136];   // [key][d], pad +8
  __shared__ __align__(16) unsigned short Vsm[128 * 72];   // [d][key], pad +8
  __shared__ __align__(16) unsigned short Psm[4][32 * 72]; // per-wave [q][key], pad +8
  __shared__ float Alds[4][32];

  const float SL2E = 0.1275378504229740f;  // (1/sqrt(128)) * log2(e)

  const unsigned short* Kb0 = QKV + (size_t)(b * SLEN) * QKVLD + 4096 + kvh * HD;
  const unsigned short* VTb = VTm + ((size_t)(b * NKV + kvh) * HD) * SLEN;

#pragma unroll 1
  for (int halfq = 0; halfq < 2; ++halfq) {
    const int qt = halfq ? (63 - pair) : pair;
    const int q0 = qt * 32;
    const int ntiles = (qt >> 1) + 1;

    // Q fragments: q = ni*16+lr, d = kd*32+lg*8
    bf16x8 qf[2][4];
    const unsigned short* Qb = QKV + (size_t)(b * SLEN + q0) * QKVLD + h * HD;
#pragma unroll
    for (int ni = 0; ni < 2; ++ni)
#pragma unroll
      for (int kd = 0; kd < 4; ++kd)
        qf[ni][kd] = *(const bf16x8*)&Qb[(size_t)(ni * 16 + lr) * QKVLD + kd * 32 + lg * 8];

    f32x4 acc_o[2][8] = {};
    float m_run[2] = {-1e30f, -1e30f};
    float l_run[2] = {0.f, 0.f};

    // prefetch tile 0 -> regs
    bf16x8 kreg[4], vreg[4];
#pragma unroll
    for (int i = 0; i < 4; ++i) {
      int c = tid + i * 256;
      kreg[i] = *(const bf16x8*)&Kb0[(size_t)(c >> 4) * QKVLD + (c & 15) * 8];
      vreg[i] = *(const bf16x8*)&VTb[(size_t)(c >> 3) * SLEN + (c & 7) * 8];
    }

#pragma unroll 1
    for (int t = 0; t < ntiles; ++t) {
      const int kv0 = t * 64;
      __syncthreads();
#pragma unroll
      for (int i = 0; i < 4; ++i) {
        int c = tid + i * 256;
        *(bf16x8*)&Ksm[(c >> 4) * 136 + (c & 15) * 8] = kreg[i];
        *(bf16x8*)&Vsm[(c >> 3) * 72 + (c & 7) * 8] = vreg[i];
      }
      __syncthreads();

      if (t + 1 < ntiles) {
#pragma unroll
        for (int i = 0; i < 4; ++i) {
          int c = tid + i * 256;
          kreg[i] = *(const bf16x8*)&Kb0[(size_t)(kv0 + 64 + (c >> 4)) * QKVLD + (c & 15) * 8];
          vreg[i] = *(const bf16x8*)&VTb[(size_t)(c >> 3) * SLEN + kv0 + 64 + (c & 7) * 8];
        }
      }

      // QK^T: S^T(64 key x 32 q) = K @ Q^T
      f32x4 accs[4][2] = {};
#pragma unroll
      for (int kd = 0; kd < 4; ++kd) {
        bf16x8 kf[4];
#pragma unroll
        for (int mi = 0; mi < 4; ++mi)
          kf[mi] = *(const bf16x8*)&Ksm[(mi * 16 + lr) * 136 + kd * 32 + lg * 8];
        __builtin_amdgcn_s_setprio(1);
#pragma unroll
        for (int mi = 0; mi < 4; ++mi)
#pragma unroll
          for (int ni = 0; ni < 2; ++ni)
            accs[mi][ni] =
                __builtin_amdgcn_mfma_f32_16x16x32_bf16(kf[mi], qf[ni][kd], accs[mi][ni], 0, 0, 0);
        __builtin_amdgcn_s_setprio(0);
      }

      // online softmax, log2*scale domain
      const bool domask = (t == ntiles - 1);
      float alpha[2];
#pragma unroll
      for (int ni = 0; ni < 2; ++ni) {
        float cmax = -1e30f;
#pragma unroll
        for (int mi = 0; mi < 4; ++mi)
#pragma unroll
          for (int r = 0; r < 4; ++r) {
            float s = accs[mi][ni][r] * SL2E;
            if (domask) {
              int key = kv0 + mi * 16 + lg * 4 + r;
              int qq = q0 + ni * 16 + lr;
              if (key > qq) s = -1e30f;
            }
            accs[mi][ni][r] = s;
            cmax = fmaxf(cmax, s);
          }
        cmax = fmaxf(cmax, __shfl_xor(cmax, 16));
        cmax = fmaxf(cmax, __shfl_xor(cmax, 32));
        float mnew = fmaxf(m_run[ni], cmax);
        alpha[ni] = exp2f(m_run[ni] - mnew);
        float psum = 0.f;
#pragma unroll
        for (int mi = 0; mi < 4; ++mi)
#pragma unroll
          for (int r = 0; r < 4; ++r) {
            float p = exp2f(accs[mi][ni][r] - mnew);
            accs[mi][ni][r] = p;
            psum += p;
          }
        psum += __shfl_xor(psum, 16);
        psum += __shfl_xor(psum, 32);
        l_run[ni] = l_run[ni] * alpha[ni] + psum;
        m_run[ni] = mnew;
      }

      // exact defer-rescale: skip when running max unchanged (alpha==1)
      if (__any(alpha[0] < 1.f) || __any(alpha[1] < 1.f)) {
        if (lg == 0) { Alds[w][lr] = alpha[0]; Alds[w][16 + lr] = alpha[1]; }
        f32x4 al0 = *(const f32x4*)&Alds[w][lg * 4];
        f32x4 al1 = *(const f32x4*)&Alds[w][16 + lg * 4];
#pragma unroll
        for (int nd = 0; nd < 8; ++nd)
#pragma unroll
          for (int r = 0; r < 4; ++r) {
            acc_o[0][nd][r] *= al0[r];
            acc_o[1][nd][r] *= al1[r];
          }
      }

      // P (S^T: row=key, col=q) -> Psm[q][key] bf16
#pragma unroll
      for (int ni = 0; ni < 2; ++ni)
#pragma unroll
        for (int mi = 0; mi < 4; ++mi)
#pragma unroll
          for (int rp = 0; rp < 4; rp += 2) {
            uint32_t pk = (uint32_t)f2bf(accs[mi][ni][rp]) |
                          ((uint32_t)f2bf(accs[mi][ni][rp + 1]) << 16);
            *(uint32_t*)&Psm[w][(ni * 16 + lr) * 72 + mi * 16 + lg * 4 + rp] = pk;
          }

      // PV: O(32q x 128d) += P(32x64) @ V(64x128)
#pragma unroll
      for (int ks = 0; ks < 2; ++ks) {
        bf16x8 pa[2];
#pragma unroll
        for (int pm = 0; pm < 2; ++pm)
          pa[pm] = *(const bf16x8*)&Psm[w][(pm * 16 + lr) * 72 + ks * 32 + lg * 8];
        __builtin_amdgcn_s_setprio(1);
#pragma unroll
        for (int nd = 0; nd < 8; ++nd) {
          bf16x8 vb = *(const bf16x8*)&Vsm[(nd * 16 + lr) * 72 + ks * 32 + lg * 8];
#pragma unroll
          for (int pm = 0; pm < 2; ++pm)
            acc_o[pm][nd] =
                __builtin_amdgcn_mfma_f32_16x16x32_bf16(pa[pm], vb, acc_o[pm][nd], 0, 0, 0);
        }
        __builtin_amdgcn_s_setprio(0);
      }
    }

    // epilogue: O /= l, store bf16 at (b, q, h, d)
    if (lg == 0) {
      Alds[w][lr] = 1.f / l_run[0];
      Alds[w][16 + lr] = 1.f / l_run[1];
    }
    f32x4 li0 = *(const f32x4*)&Alds[w][lg * 4];
    f32x4 li1 = *(const f32x4*)&Alds[w][16 + lg * 4];
    unsigned short* Ob = Om + ((size_t)(b * SLEN + q0) * NH + h) * HD;
#pragma unroll
    for (int pm = 0; pm < 2; ++pm)
#pragma unroll
      for (int nd = 0; nd < 8; ++nd)
#pragma unroll
        for (int r = 0; r < 4; ++r) {
          int qq = pm * 16 + lg * 4 + r;
          float v = acc_o[pm][nd][r] * (pm ? li1[r] : li0[r]);
          Ob[(size_t)qq * (NH * HD) + nd * 16 + lr] = f2bf(v);
        }
  }
}

// ---------------------------------------------------------------------------
// Launcher.  d_in: hidden, attention_mask(unused: known causal), wq, wk, wv, wo
// Workspace (169 MB): Xbf 32 | Wqkv 48 | QKV 48 | Ob 32 | VTb 8 | ct/st 1
// ---------------------------------------------------------------------------
extern "C" void kernel_launch(void* const* d_in, const int* in_sizes, int n_in,
                              void* d_out, int out_size, void* d_ws, size_t ws_size,
                              hipStream_t stream) {
  const float* hidden = (const float*)d_in[0];
  const float* wq = (const float*)d_in[2];
  const float* wk = (const float*)d_in[3];
  const float* wv = (const float*)d_in[4];
  const float* wo = (const float*)d_in[5];

  char* ws = (char*)d_ws;
  const size_t MB = 1ull << 20;
  unsigned short* Xbf  = (unsigned short*)(ws);             // 32 MB (B*S,4096)
  unsigned short* Wqkv = (unsigned short*)(ws + 32 * MB);   // 48 MB (6144,4096) packed W
  unsigned short* QKV  = (unsigned short*)(ws + 80 * MB);   // 48 MB (B*S,6144)
  unsigned short* Ob   = (unsigned short*)(ws + 128 * MB);  // 32 MB (B*S,4096)
  unsigned short* VTb  = (unsigned short*)(ws + 160 * MB);  // 8 MB (B,8,128,S)
  float* ct = (float*)(ws + 168 * MB);                      // 0.5 MB
  float* st = (float*)(ws + 168 * MB + 524288);             // 0.5 MB

  // 1) bf16 casts (weights packed: Wq rows 0..4095, Wk 4096..5119, Wv 5120..6143)
  cvt_f32_bf16<<<8192, 256, 0, stream>>>(hidden, Xbf);
  cvt_f32_bf16<<<8192, 256, 0, stream>>>(wq, Wqkv);
  cvt_f32_bf16<<<2048, 256, 0, stream>>>(wk, Wqkv + (size_t)4096 * 4096);
  cvt_f32_bf16<<<2048, 256, 0, stream>>>(wv, Wqkv + (size_t)5120 * 4096);

  // 2) fused QKV projection: (4096,4096) @ (6144,4096)^T -> (4096,6144)
  gemm_bt256<unsigned short><<<384, 512, 0, stream>>>(Xbf, Wqkv, QKV, 4096, 6144, 4096);

  // 3) RoPE on Q and K columns of fused buffer
  rope_tables<<<512, 256, 0, stream>>>(ct, st);
  rope_apply<<<4096, 256, 0, stream>>>(QKV, QKVLD, ct, st, NH);
  rope_apply<<<1024, 256, 0, stream>>>(QKV + 4096, QKVLD, ct, st, NKV);

  // 4) V -> V^T
  transpose_v<<<dim3(64, 16), 256, 0, stream>>>(QKV + 5120, QKVLD, VTb);

  // 5) causal GQA flash attention (paired q-tiles, XCD-grouped)
  attn_fwd<<<512, 256, 0, stream>>>(QKV, VTb, Ob);

  // 6) output projection (fp32 out); Wqkv region reused for Wo
  cvt_f32_bf16<<<8192, 256, 0, stream>>>(wo, Wqkv);
  gemm_bt256<float><<<256, 512, 0, stream>>>(Ob, Wqkv, (float*)d_out, 4096, 4096, 4096);
}

// Round 9
// 575.530 us; speedup vs baseline: 1.0256x; 1.0256x over previous
//
#include <hip/hip_runtime.h>
#include <hip/hip_bf16.h>
#include <stdint.h>

// ---------------------------------------------------------------------------
// GroupedQueryAttention: hidden(B,S,4096) -> fused QKV proj -> RoPE -> causal
// GQA flash attention -> out proj.  B=2 S=2048 H=32 Hk=8 D=128.  bf16 MFMA.
// ---------------------------------------------------------------------------

#define HIDDEN 4096
#define NH 32
#define NKV 8
#define HD 128
#define SLEN 2048
#define BATCH 2
#define QKVLD 6144  // fused QKV row stride (cols: Q 0..4095, K 4096..5119, V 5120..6143)

typedef __attribute__((ext_vector_type(8))) short bf16x8;
typedef __attribute__((ext_vector_type(4))) float f32x4;

__device__ __forceinline__ unsigned short f2bf(float f) {
  __hip_bfloat16 h = __float2bfloat16(f);
  return *reinterpret_cast<unsigned short*>(&h);
}
__device__ __forceinline__ float bf2f(unsigned short h) {
  union { uint32_t u; float f; } v; v.u = ((uint32_t)h) << 16;
  return v.f;
}
__device__ __forceinline__ void gload_lds16(const void* g, void* l) {
  __builtin_amdgcn_global_load_lds(
      (const __attribute__((address_space(1))) unsigned int*)g,
      (__attribute__((address_space(3))) unsigned int*)l, 16, 0, 0);
}

// ---------------------------------------------------------------------------
// fp32 -> bf16 convert, 8 elems/thread. n = grid*2048 exactly.
// ---------------------------------------------------------------------------
__global__ __launch_bounds__(256) void cvt_f32_bf16(const float* __restrict__ in,
                                                    unsigned short* __restrict__ out) {
  size_t i = ((size_t)blockIdx.x * 256 + threadIdx.x) * 8;
  f32x4 a = *(const f32x4*)&in[i];
  f32x4 b = *(const f32x4*)&in[i + 4];
  bf16x8 o;
#pragma unroll
  for (int j = 0; j < 4; ++j) { o[j] = (short)f2bf(a[j]); o[4 + j] = (short)f2bf(b[j]); }
  *(bf16x8*)&out[i] = o;
}

// ---------------------------------------------------------------------------
// GEMM  C(M,N) = A(M,K) @ B(N,K)^T, bf16 in, OutT out.
// 8-phase m201 schedule (r8) + strength-reduced addressing (r9):
//  - t-loop unrolled x2 -> buffer parity compile-time -> ds_reads become
//    base + immediate offset (no per-phase address VALU).
//  - stage global srcs precomputed per thread (row*K hoisted out of loop);
//    per stage only +tile*64 uniform offset.  LDS dests constant.
//  - boundary vmcnt merged into phase 4 (8 barriers/tile, counted vmcnt(6)).
// LDS = 2 buffers x 64KB = {A-k0|A-k1|B-k0|B-k1} x [256 rows][4 chunks].
// Swizzle (verified r5, conflicts=0): source chunk cc^((row>>1)&3), read
// slot lg^((lr>>1)&3).  M,N multiples of 256; K multiple of 128; grid%8==0.
// ---------------------------------------------------------------------------
__device__ __forceinline__ void store_out(unsigned short* C, size_t i, float v) { C[i] = f2bf(v); }
__device__ __forceinline__ void store_out(float* C, size_t i, float v) { C[i] = v; }

template <typename OutT>
__global__ __launch_bounds__(512, 2)
void gemm_bt256(const unsigned short* __restrict__ A, const unsigned short* __restrict__ B,
                OutT* __restrict__ C, int M, int N, int K) {
  __shared__ __align__(16) unsigned short lds[2 * 4096 * 8];

  const int tid = threadIdx.x;
  const int lane = tid & 63, w = tid >> 6;
  const int lr = lane & 15, lg = lane >> 4;
  const int wr = w >> 2, wc = w & 3;  // 2 x 4 wave grid
  const int rsw = (lr >> 1) & 3;

  const int nbn = N >> 8;
  const int nwg = gridDim.x;
  int wg = (int)blockIdx.x;
  wg = (wg & 7) * (nwg >> 3) + (wg >> 3);  // XCD-aware swizzle (nwg%8==0)
  const int bm = wg / nbn, bn = wg % nbn;

  const unsigned short* Ab = A + (size_t)bm * 256 * K;
  const unsigned short* Bb = B + (size_t)bn * 256 * K;

  // stage source pointers: constant per thread (swizzled col-chunk), K-mul hoisted
  const int r0 = tid >> 2, s0 = (tid & 3) ^ ((tid >> 3) & 3);
  const int L1 = tid + 512;
  const int r1 = L1 >> 2, s1 = (L1 & 3) ^ ((L1 >> 3) & 3);
  const unsigned short* gA0 = Ab + (size_t)r0 * K + s0 * 8;
  const unsigned short* gA1 = Ab + (size_t)r1 * K + s1 * 8;
  const unsigned short* gB0 = Bb + (size_t)r0 * K + s0 * 8;
  const unsigned short* gB1 = Bb + (size_t)r1 * K + s1 * 8;

  // LDS read base pointers (ushort units; buffer stride = 4096 chunks = 32768)
  const unsigned short* rdA0 = &lds[(size_t)(wr * 512 + lr * 4 + (lg ^ rsw)) * 8];
  const unsigned short* rdA1 = rdA0 + 32768;
  const unsigned short* rdB0 = &lds[(size_t)(2048 + wc * 256 + lr * 4 + (lg ^ rsw)) * 8];
  const unsigned short* rdB1 = rdB0 + 32768;

  f32x4 acc[8][4] = {};

  // stage one half-tile (A or B, 16KB, 2 gload_lds16/thread)
  auto stageA = [&](int ks, int tile) {
    unsigned short* d = &lds[(size_t)((tile & 1) * 4096 + ks * 1024 + tid) * 8];
    const int off = tile * 64 + ks * 32;
    gload_lds16(gA0 + off, d);
    gload_lds16(gA1 + off, d + 4096);  // +512 chunks
  };
  auto stageB = [&](int ks, int tile) {
    unsigned short* d = &lds[(size_t)((tile & 1) * 4096 + 2048 + ks * 1024 + tid) * 8];
    const int off = tile * 64 + ks * 32;
    gload_lds16(gB0 + off, d);
    gload_lds16(gB1 + off, d + 4096);
  };

  const int NT = K >> 6;  // K multiple of 128 -> NT even

#define PHASE_SYNC()                                  \
  __builtin_amdgcn_s_barrier();                       \
  asm volatile("s_waitcnt lgkmcnt(0)" ::: "memory");  \
  __builtin_amdgcn_sched_barrier(0)

#define MFMA16(afq, bq, mb)                                                       \
  __builtin_amdgcn_s_setprio(1);                                                  \
  _Pragma("unroll") for (int i_ = 0; i_ < 4; ++i_)                                \
  _Pragma("unroll") for (int n_ = 0; n_ < 4; ++n_)                                \
    acc[(mb) + i_][n_] = __builtin_amdgcn_mfma_f32_16x16x32_bf16(                 \
        afq[i_], bq[n_], acc[(mb) + i_][n_], 0, 0, 0);                            \
  __builtin_amdgcn_s_setprio(0)

// reads: base + compile-time offset (P, ks, mi literal after expansion)
#define RD_A(dst, P, ks, mi0)                                                     \
  _Pragma("unroll") for (int i_ = 0; i_ < 4; ++i_)                                \
    dst[i_] = *(const bf16x8*)((P ? rdA1 : rdA0) + (ks) * 8192 + ((mi0) + i_) * 512)
#define RD_B(dst, P, ks)                                                          \
  _Pragma("unroll") for (int i_ = 0; i_ < 4; ++i_)                                \
    dst[i_] = *(const bf16x8*)((P ? rdB1 : rdB0) + (ks) * 8192 + i_ * 512)

#define TILE_BODY(P, t)                                                           \
  {                                                                               \
    bf16x8 a0[4], a1[4], b0[4], b1[4];                                            \
    /* ph1: read A-k0 lo + B-k0 | stage A-k1(t+1) | MFMA k0 lo */                 \
    RD_A(a0, P, 0, 0); RD_B(b0, P, 0);                                            \
    if ((t) + 1 < NT) stageA(1, (t) + 1);                                         \
    PHASE_SYNC();                                                                 \
    MFMA16(a0, b0, 0);                                                            \
    __builtin_amdgcn_s_barrier();                                                 \
    /* ph2: read A-k0 hi | stage B-k0(t+2) | MFMA k0 hi */                        \
    RD_A(a1, P, 0, 4);                                                            \
    if ((t) + 2 < NT) stageB(0, (t) + 2);                                         \
    PHASE_SYNC();                                                                 \
    MFMA16(a1, b0, 4);                                                            \
    __builtin_amdgcn_s_barrier();                                                 \
    /* ph3: read A-k1 lo + B-k1 | stage A-k0(t+2) | MFMA k1 lo */                 \
    RD_A(a0, P, 1, 0); RD_B(b1, P, 1);                                            \
    if ((t) + 2 < NT) stageA(0, (t) + 2);                                         \
    PHASE_SYNC();                                                                 \
    MFMA16(a0, b1, 0);                                                            \
    __builtin_amdgcn_s_barrier();                                                 \
    /* ph4: read A-k1 hi | stage B-k1(t+2) | MFMA k1 hi | counted vmcnt */        \
    RD_A(a1, P, 1, 4);                                                            \
    if ((t) + 2 < NT) stageB(1, (t) + 2);                                         \
    PHASE_SYNC();                                                                 \
    MFMA16(a1, b1, 4);                                                            \
    if ((t) + 2 < NT)      asm volatile("s_waitcnt vmcnt(6)" ::: "memory");       \
    else if ((t) + 1 < NT) asm volatile("s_waitcnt vmcnt(0)" ::: "memory");       \
    __builtin_amdgcn_s_barrier();                                                 \
  }

  // prologue: tile0 (4 halves) + tile1 {B-k0, A-k0, B-k1}; A-k1(1) comes in ph1
  stageA(0, 0); stageB(0, 0); stageA(1, 0); stageB(1, 0);
  stageB(0, 1); stageA(0, 1); stageB(1, 1);
  asm volatile("s_waitcnt vmcnt(6)" ::: "memory");
  __builtin_amdgcn_s_barrier();
  asm volatile("" ::: "memory");

#pragma unroll 1
  for (int t = 0; t < NT; t += 2) {
    TILE_BODY(0, t);
    TILE_BODY(1, t + 1);
  }

#pragma unroll
  for (int mi = 0; mi < 8; ++mi)
#pragma unroll
    for (int ni = 0; ni < 4; ++ni)
#pragma unroll
      for (int r = 0; r < 4; ++r) {
        size_t row = (size_t)bm * 256 + wr * 128 + mi * 16 + lg * 4 + r;
        size_t col = (size_t)bn * 256 + wc * 64 + ni * 16 + lr;
        store_out(C, row * N + col, acc[mi][ni][r]);
      }
#undef PHASE_SYNC
#undef MFMA16
#undef RD_A
#undef RD_B
#undef TILE_BODY
}

// ---------------------------------------------------------------------------
// RoPE tables + apply
// ---------------------------------------------------------------------------
__global__ __launch_bounds__(256) void rope_tables(float* __restrict__ ct, float* __restrict__ st) {
  int idx = blockIdx.x * 256 + threadIdx.x;  // S*64
  int s = idx >> 6, j = idx & 63;
  float inv = exp2f(-(float)j * (13.287712379549449f / 64.f));
  float f = (float)s * inv;
  ct[idx] = cosf(f);
  st[idx] = sinf(f);
}

__global__ __launch_bounds__(256) void rope_apply(unsigned short* __restrict__ X, int ld,
                                                  const float* __restrict__ ct,
                                                  const float* __restrict__ st, int heads) {
  int idx = blockIdx.x * 256 + threadIdx.x;
  int jc = (idx & 7) * 8;
  int t2 = idx >> 3;
  int hh = t2 % heads;
  int row = t2 / heads;
  int s = row & (SLEN - 1);
  unsigned short* p = X + (size_t)row * ld + hh * HD;
  bf16x8 lo = *(bf16x8*)&p[jc];
  bf16x8 hi = *(bf16x8*)&p[64 + jc];
  bf16x8 nlo, nhi;
#pragma unroll
  for (int j = 0; j < 8; ++j) {
    float c = ct[s * 64 + jc + j];
    float sn = st[s * 64 + jc + j];
    float xl = bf2f((unsigned short)(lo[j]));
    float xh = bf2f((unsigned short)(hi[j]));
    nlo[j] = (short)f2bf(xl * c - xh * sn);
    nhi[j] = (short)f2bf(xh * c + xl * sn);
  }
  *(bf16x8*)&p[jc] = nlo;
  *(bf16x8*)&p[64 + jc] = nhi;
}

// ---------------------------------------------------------------------------
// V (rows B*S at stride ld, 1024 cols) -> VT (B, NKV, HD, S)
// ---------------------------------------------------------------------------
__global__ __launch_bounds__(256) void transpose_v(const unsigned short* __restrict__ Vsrc, int ld,
                                                   unsigned short* __restrict__ VT) {
  __shared__ unsigned short tile[64][66];
  const int t = threadIdx.x;
  const int bs = blockIdx.x;
  const int bd = blockIdx.y;
  const int b = bs >> 5;
  const int s0 = (bs & 31) * 64;
  const int d0 = bd * 64;
#pragma unroll
  for (int it = 0; it < 2; ++it) {
    int si = (t >> 3) + it * 32;
    int dj = (t & 7) * 8;
    bf16x8 v = *(const bf16x8*)&Vsrc[(size_t)(b * SLEN + s0 + si) * ld + d0 + dj];
#pragma unroll
    for (int j = 0; j < 8; ++j) tile[si][dj + j] = (unsigned short)(v[j]);
  }
  __syncthreads();
#pragma unroll
  for (int it = 0; it < 2; ++it) {
    int di = (t >> 3) + it * 32;
    int sj = (t & 7) * 8;
    bf16x8 o;
#pragma unroll
    for (int j = 0; j < 8; ++j) o[j] = (short)tile[sj + j][di];
    int c = d0 + di;
    int kvh = c >> 7, d = c & 127;
    *(bf16x8*)&VT[(((size_t)b * NKV + kvh) * HD + d) * SLEN + s0 + sj] = o;
  }
}

// ---------------------------------------------------------------------------
// Flash attention (round-3 version, validated).
// ---------------------------------------------------------------------------
__global__ __launch_bounds__(256, 2)
void attn_fwd(const unsigned short* __restrict__ QKV, const unsigned short* __restrict__ VTm,
              unsigned short* __restrict__ Om) {
  const int blk = blockIdx.x;            // 0..511
  const int xcd = blk & 7, jj = blk >> 3;
  const int g = xcd + ((jj >> 5) << 3);  // (b,kvh) group 0..15, pinned per XCD
  const int pair = jj & 31;
  const int kvh = g & 7, b = g >> 3;
  const int tid = threadIdx.x;
  const int lane = tid & 63, w = tid >> 6;
  const int lr = lane & 15, lg = lane >> 4;
  const int h = kvh * 4 + w;

  __shared__ __align__(16) unsigned short Ksm[64 * 136];   // [key][d], pad +8
  __shared__ __align__(16) unsigned short Vsm[128 * 72];   // [d][key], pad +8
  __shared__ __align__(16) unsigned short Psm[4][32 * 72]; // per-wave [q][key], pad +8
  __shared__ float Alds[4][32];

  const float SL2E = 0.1275378504229740f;  // (1/sqrt(128)) * log2(e)

  const unsigned short* Kb0 = QKV + (size_t)(b * SLEN) * QKVLD + 4096 + kvh * HD;
  const unsigned short* VTb = VTm + ((size_t)(b * NKV + kvh) * HD) * SLEN;

#pragma unroll 1
  for (int halfq = 0; halfq < 2; ++halfq) {
    const int qt = halfq ? (63 - pair) : pair;
    const int q0 = qt * 32;
    const int ntiles = (qt >> 1) + 1;

    // Q fragments: q = ni*16+lr, d = kd*32+lg*8
    bf16x8 qf[2][4];
    const unsigned short* Qb = QKV + (size_t)(b * SLEN + q0) * QKVLD + h * HD;
#pragma unroll
    for (int ni = 0; ni < 2; ++ni)
#pragma unroll
      for (int kd = 0; kd < 4; ++kd)
        qf[ni][kd] = *(const bf16x8*)&Qb[(size_t)(ni * 16 + lr) * QKVLD + kd * 32 + lg * 8];

    f32x4 acc_o[2][8] = {};
    float m_run[2] = {-1e30f, -1e30f};
    float l_run[2] = {0.f, 0.f};

    // prefetch tile 0 -> regs
    bf16x8 kreg[4], vreg[4];
#pragma unroll
    for (int i = 0; i < 4; ++i) {
      int c = tid + i * 256;
      kreg[i] = *(const bf16x8*)&Kb0[(size_t)(c >> 4) * QKVLD + (c & 15) * 8];
      vreg[i] = *(const bf16x8*)&VTb[(size_t)(c >> 3) * SLEN + (c & 7) * 8];
    }

#pragma unroll 1
    for (int t = 0; t < ntiles; ++t) {
      const int kv0 = t * 64;
      __syncthreads();
#pragma unroll
      for (int i = 0; i < 4; ++i) {
        int c = tid + i * 256;
        *(bf16x8*)&Ksm[(c >> 4) * 136 + (c & 15) * 8] = kreg[i];
        *(bf16x8*)&Vsm[(c >> 3) * 72 + (c & 7) * 8] = vreg[i];
      }
      __syncthreads();

      if (t + 1 < ntiles) {
#pragma unroll
        for (int i = 0; i < 4; ++i) {
          int c = tid + i * 256;
          kreg[i] = *(const bf16x8*)&Kb0[(size_t)(kv0 + 64 + (c >> 4)) * QKVLD + (c & 15) * 8];
          vreg[i] = *(const bf16x8*)&VTb[(size_t)(c >> 3) * SLEN + kv0 + 64 + (c & 7) * 8];
        }
      }

      // QK^T: S^T(64 key x 32 q) = K @ Q^T
      f32x4 accs[4][2] = {};
#pragma unroll
      for (int kd = 0; kd < 4; ++kd) {
        bf16x8 kf[4];
#pragma unroll
        for (int mi = 0; mi < 4; ++mi)
          kf[mi] = *(const bf16x8*)&Ksm[(mi * 16 + lr) * 136 + kd * 32 + lg * 8];
        __builtin_amdgcn_s_setprio(1);
#pragma unroll
        for (int mi = 0; mi < 4; ++mi)
#pragma unroll
          for (int ni = 0; ni < 2; ++ni)
            accs[mi][ni] =
                __builtin_amdgcn_mfma_f32_16x16x32_bf16(kf[mi], qf[ni][kd], accs[mi][ni], 0, 0, 0);
        __builtin_amdgcn_s_setprio(0);
      }

      // online softmax, log2*scale domain
      const bool domask = (t == ntiles - 1);
      float alpha[2];
#pragma unroll
      for (int ni = 0; ni < 2; ++ni) {
        float cmax = -1e30f;
#pragma unroll
        for (int mi = 0; mi < 4; ++mi)
#pragma unroll
          for (int r = 0; r < 4; ++r) {
            float s = accs[mi][ni][r] * SL2E;
            if (domask) {
              int key = kv0 + mi * 16 + lg * 4 + r;
              int qq = q0 + ni * 16 + lr;
              if (key > qq) s = -1e30f;
            }
            accs[mi][ni][r] = s;
            cmax = fmaxf(cmax, s);
          }
        cmax = fmaxf(cmax, __shfl_xor(cmax, 16));
        cmax = fmaxf(cmax, __shfl_xor(cmax, 32));
        float mnew = fmaxf(m_run[ni], cmax);
        alpha[ni] = exp2f(m_run[ni] - mnew);
        float psum = 0.f;
#pragma unroll
        for (int mi = 0; mi < 4; ++mi)
#pragma unroll
          for (int r = 0; r < 4; ++r) {
            float p = exp2f(accs[mi][ni][r] - mnew);
            accs[mi][ni][r] = p;
            psum += p;
          }
        psum += __shfl_xor(psum, 16);
        psum += __shfl_xor(psum, 32);
        l_run[ni] = l_run[ni] * alpha[ni] + psum;
        m_run[ni] = mnew;
      }

      // exact defer-rescale: skip when running max unchanged (alpha==1)
      if (__any(alpha[0] < 1.f) || __any(alpha[1] < 1.f)) {
        if (lg == 0) { Alds[w][lr] = alpha[0]; Alds[w][16 + lr] = alpha[1]; }
        f32x4 al0 = *(const f32x4*)&Alds[w][lg * 4];
        f32x4 al1 = *(const f32x4*)&Alds[w][16 + lg * 4];
#pragma unroll
        for (int nd = 0; nd < 8; ++nd)
#pragma unroll
          for (int r = 0; r < 4; ++r) {
            acc_o[0][nd][r] *= al0[r];
            acc_o[1][nd][r] *= al1[r];
          }
      }

      // P (S^T: row=key, col=q) -> Psm[q][key] bf16
#pragma unroll
      for (int ni = 0; ni < 2; ++ni)
#pragma unroll
        for (int mi = 0; mi < 4; ++mi)
#pragma unroll
          for (int rp = 0; rp < 4; rp += 2) {
            uint32_t pk = (uint32_t)f2bf(accs[mi][ni][rp]) |
                          ((uint32_t)f2bf(accs[mi][ni][rp + 1]) << 16);
            *(uint32_t*)&Psm[w][(ni * 16 + lr) * 72 + mi * 16 + lg * 4 + rp] = pk;
          }

      // PV: O(32q x 128d) += P(32x64) @ V(64x128)
#pragma unroll
      for (int ks = 0; ks < 2; ++ks) {
        bf16x8 pa[2];
#pragma unroll
        for (int pm = 0; pm < 2; ++pm)
          pa[pm] = *(const bf16x8*)&Psm[w][(pm * 16 + lr) * 72 + ks * 32 + lg * 8];
        __builtin_amdgcn_s_setprio(1);
#pragma unroll
        for (int nd = 0; nd < 8; ++nd) {
          bf16x8 vb = *(const bf16x8*)&Vsm[(nd * 16 + lr) * 72 + ks * 32 + lg * 8];
#pragma unroll
          for (int pm = 0; pm < 2; ++pm)
            acc_o[pm][nd] =
                __builtin_amdgcn_mfma_f32_16x16x32_bf16(pa[pm], vb, acc_o[pm][nd], 0, 0, 0);
        }
        __builtin_amdgcn_s_setprio(0);
      }
    }

    // epilogue: O /= l, store bf16 at (b, q, h, d)
    if (lg == 0) {
      Alds[w][lr] = 1.f / l_run[0];
      Alds[w][16 + lr] = 1.f / l_run[1];
    }
    f32x4 li0 = *(const f32x4*)&Alds[w][lg * 4];
    f32x4 li1 = *(const f32x4*)&Alds[w][16 + lg * 4];
    unsigned short* Ob = Om + ((size_t)(b * SLEN + q0) * NH + h) * HD;
#pragma unroll
    for (int pm = 0; pm < 2; ++pm)
#pragma unroll
      for (int nd = 0; nd < 8; ++nd)
#pragma unroll
        for (int r = 0; r < 4; ++r) {
          int qq = pm * 16 + lg * 4 + r;
          float v = acc_o[pm][nd][r] * (pm ? li1[r] : li0[r]);
          Ob[(size_t)qq * (NH * HD) + nd * 16 + lr] = f2bf(v);
        }
  }
}

// ---------------------------------------------------------------------------
// Launcher.  d_in: hidden, attention_mask(unused: known causal), wq, wk, wv, wo
// Workspace (169 MB): Xbf 32 | Wqkv 48 | QKV 48 | Ob 32 | VTb 8 | ct/st 1
// ---------------------------------------------------------------------------
extern "C" void kernel_launch(void* const* d_in, const int* in_sizes, int n_in,
                              void* d_out, int out_size, void* d_ws, size_t ws_size,
                              hipStream_t stream) {
  const float* hidden = (const float*)d_in[0];
  const float* wq = (const float*)d_in[2];
  const float* wk = (const float*)d_in[3];
  const float* wv = (const float*)d_in[4];
  const float* wo = (const float*)d_in[5];

  char* ws = (char*)d_ws;
  const size_t MB = 1ull << 20;
  unsigned short* Xbf  = (unsigned short*)(ws);             // 32 MB (B*S,4096)
  unsigned short* Wqkv = (unsigned short*)(ws + 32 * MB);   // 48 MB (6144,4096) packed W
  unsigned short* QKV  = (unsigned short*)(ws + 80 * MB);   // 48 MB (B*S,6144)
  unsigned short* Ob   = (unsigned short*)(ws + 128 * MB);  // 32 MB (B*S,4096)
  unsigned short* VTb  = (unsigned short*)(ws + 160 * MB);  // 8 MB (B,8,128,S)
  float* ct = (float*)(ws + 168 * MB);                      // 0.5 MB
  float* st = (float*)(ws + 168 * MB + 524288);             // 0.5 MB

  // 1) bf16 casts (weights packed: Wq rows 0..4095, Wk 4096..5119, Wv 5120..6143)
  cvt_f32_bf16<<<8192, 256, 0, stream>>>(hidden, Xbf);
  cvt_f32_bf16<<<8192, 256, 0, stream>>>(wq, Wqkv);
  cvt_f32_bf16<<<2048, 256, 0, stream>>>(wk, Wqkv + (size_t)4096 * 4096);
  cvt_f32_bf16<<<2048, 256, 0, stream>>>(wv, Wqkv + (size_t)5120 * 4096);

  // 2) fused QKV projection: (4096,4096) @ (6144,4096)^T -> (4096,6144)
  gemm_bt256<unsigned short><<<1536 / 4, 512, 0, stream>>>(Xbf, Wqkv, QKV, 4096, 6144, 4096);

  // 3) RoPE on Q and K columns of fused buffer
  rope_tables<<<512, 256, 0, stream>>>(ct, st);
  rope_apply<<<4096, 256, 0, stream>>>(QKV, QKVLD, ct, st, NH);
  rope_apply<<<1024, 256, 0, stream>>>(QKV + 4096, QKVLD, ct, st, NKV);

  // 4) V -> V^T
  transpose_v<<<dim3(64, 16), 256, 0, stream>>>(QKV + 5120, QKVLD, VTb);

  // 5) causal GQA flash attention (paired q-tiles, XCD-grouped)
  attn_fwd<<<512, 256, 0, stream>>>(QKV, VTb, Ob);

  // 6) output projection (fp32 out); Wqkv region reused for Wo
  cvt_f32_bf16<<<8192, 256, 0, stream>>>(wo, Wqkv);
  gemm_bt256<float><<<256, 512, 0, stream>>>(Ob, Wqkv, (float*)d_out, 4096, 4096, 4096);
}